// Round 11
// baseline (1204.318 us; speedup 1.0000x reference)
//
#include <hip/hip_runtime.h>
#include <cstddef>

// ---------------------------------------------------------------------------
// SNN forward, feed-forward pipeline. CORRECTNESS CONTRACT: reproduce R3's
// sequential-in-ascending-j fp32 fmaf chain per (t,b,o) (passed, 1.5e-5).
// R10 FACT: fmaf(+0, w, acc) == acc EXACTLY (acc never -0), so skipping
// zero-spike j's is bit-identical. R10 (WIN 1190us) proved it at VALUBusy 50%
// — latency-bound on per-j ds_read + 128 dbuf barriers at 2 waves/SIMD.
//
// R11: NO LDS AT ALL. Per active j, lanes load their 16B W-row slice straight
// from L2 (WT1 = 4MB = one XCD L2; 1KB/wave coalesced). Loads for a 4-j
// group are batch-issued BEFORE the FMA bodies (independent vmcnt slots cover
// ~200cyc L2 latency against ~1024cyc FMA). Zero barriers, zero staging.
//   - j skipped via wave-uniform scalar branch (mask word == 0)
//   - per-t gate on the scalar pipe (av = SGPR operand to v_fmac)
//   - t lives in registers (acc[32][NAO]); LIF/LI epilogue all-register
// R4/R5/R7 lesson: acc static-indexed, no big reg prefetch, bounds(256,2).
// ---------------------------------------------------------------------------

#define THREADS 256

typedef float f4v __attribute__((ext_vector_type(4)));
typedef float f2v __attribute__((ext_vector_type(2)));

// WT offsets (floats): WT1[2048][512], WT2[512][512], WT3[512][256],
// WT4[256][128] (w4 zero-padded 100->128 cols)
#define WOFF1 0
#define WOFF2 1048576
#define WOFF3 1310720
#define WOFF4 1441792
#define WTOT  1474560

__global__ __launch_bounds__(THREADS) void prep_kernel(
    const float* __restrict__ w1, const float* __restrict__ w2,
    const float* __restrict__ w3, const float* __restrict__ w4,
    float* __restrict__ wt)
{
  int idx = blockIdx.x * THREADS + threadIdx.x;
  if (idx >= WTOT) return;
  if (idx < WOFF2) {
    int j = idx >> 9, o = idx & 511;
    wt[idx] = w1[o * 2048 + j];
  } else if (idx < WOFF3) {
    int r = idx - WOFF2, j = r >> 9, o = r & 511;
    wt[idx] = w2[o * 512 + j];
  } else if (idx < WOFF4) {
    int r = idx - WOFF3, j = r >> 8, o = r & 255;
    wt[idx] = w3[o * 512 + j];
  } else {
    int r = idx - WOFF4, j = r >> 7, o = r & 127;
    wt[idx] = (o < 100) ? w4[o * 256 + j] : 0.0f;
  }
}

// Encoder (verbatim R3 arithmetic); writes em[b][j] word = bits over t.
__global__ __launch_bounds__(THREADS) void enc_kernel(
    const float* __restrict__ x, const float* __restrict__ fscale,
    unsigned* __restrict__ em, int b0)
{
  int idx = blockIdx.x * THREADS + threadIdx.x;
  int b = idx >> 11, j = idx & 2047;
  float c = 2.0f * fscale[0] * x[((size_t)(b0 + b) << 11) + j];
  float v = 0.0f;
  unsigned m = 0u;
#pragma unroll
  for (int t = 0; t < 32; ++t) {
    v = v + 0.1f * (c - v);
    unsigned z = ((v - 0.33f) > 0.0f) ? 1u : 0u;
    m |= z << t;
    if (z) v = 0.0f;
  }
  em[idx] = m;
}

// ---------------------------------------------------------------------------
// Sparse-j fused GEMM(+LIF / +LI readout), LDS-free.
//   mIn: em-format masks [b][J], word = bits over t (wave-uniform per j)
//   WT:  [j][o] pre-transposed weights (rows L2-resident)
// Block: 4 waves; wave = (b, o-slice); lane owns NAO consecutive o's,
// acc[32][NAO] holds all t. j skipped when word==0 (bit-exact identity).
// ---------------------------------------------------------------------------
template <int O, bool FINAL>
__global__ __launch_bounds__(THREADS, 2) void gemm_sparse(
    const unsigned* __restrict__ mIn, const float* __restrict__ WT,
    int J, const float* __restrict__ es,
    unsigned* __restrict__ mOut, float* __restrict__ out, int bbase)
{
  constexpr int NAO = (O >= 256) ? 4 : 2;    // o's per lane
  constexpr int WPB = O / (64 * NAO);        // waves per b (2 for O=512)
  constexpr int BPB = 4 / WPB;               // b's per block
  typedef float fv __attribute__((ext_vector_type(NAO)));
  const int tid = threadIdx.x;
  const int lane = tid & 63, wvid = tid >> 6;
  const int b = blockIdx.x * BPB + wvid / WPB;
  const int obase = (wvid % WPB) * (64 * NAO) + lane * NAO;
  const float* const wbase = WT + obase;     // row j at wbase + j*O
  float scalef = es ? 5.0f * es[0] : 1.0f;   // same expr as R3
  const int scale_i =
      __builtin_amdgcn_readfirstlane(__float_as_int(scalef));

  float acc[32][NAO];
#pragma unroll
  for (int t = 0; t < 32; ++t)
#pragma unroll
    for (int k = 0; k < NAO; ++k) acc[t][k] = 0.0f;

  const unsigned* mrow = mIn + (size_t)b * J;

  for (int j0 = 0; j0 < J; j0 += 4) {
    const uint4 mq = *(const uint4*)(mrow + j0);   // wave-uniform address
    unsigned w[4];
    w[0] = (unsigned)__builtin_amdgcn_readfirstlane((int)mq.x);
    w[1] = (unsigned)__builtin_amdgcn_readfirstlane((int)mq.y);
    w[2] = (unsigned)__builtin_amdgcn_readfirstlane((int)mq.z);
    w[3] = (unsigned)__builtin_amdgcn_readfirstlane((int)mq.w);

    // phase 1: batch-issue the (conditional) W-row loads — independent
    // vmcnt slots, latency overlapped against phase 2's FMA stream
    fv wv[4];
#pragma unroll
    for (int jj = 0; jj < 4; ++jj)
      if (w[jj]) wv[jj] = *(const fv*)(wbase + (size_t)(j0 + jj) * O);

    // phase 2: FMA bodies in ascending-j order (bit-identical chain)
#pragma unroll
    for (int jj = 0; jj < 4; ++jj) {
      if (w[jj]) {
#pragma unroll
        for (int t = 0; t < 32; ++t) {
          // av = bit(w,t) ? scale : 0 — scalar-pipe ops, SGPR fmaf operand
          float av = __int_as_float(
              (int)((((int)(w[jj] << (31 - t))) >> 31) & scale_i));
#pragma unroll
          for (int k = 0; k < NAO; ++k)
            acc[t][k] = fmaf(av, wv[jj][k], acc[t][k]);
        }
      }
    }
  }

  // ---- epilogue: all in registers (t lives in the lane), no barriers ----
#pragma unroll
  for (int k = 0; k < NAO; ++k) {
    if (FINAL) {
      float v = 0.0f, cur = 0.0f;
#pragma unroll
      for (int t2 = 0; t2 < 32; ++t2) {      // verbatim R3 out_li
        v = v + 0.1f * (cur - v);
        cur = 0.8f * cur + acc[t2][k];
      }
      int o = obase + k;
      if (o < 100) out[(size_t)(bbase + b) * 100 + o] = v;
    } else {
      float v = 0.0f, cur = 0.0f;
      unsigned zw = 0u;
#pragma unroll
      for (int t2 = 0; t2 < 32; ++t2) {      // verbatim R3 lif_int
        v = v + 0.1f * (cur - v);
        unsigned z = ((v - 0.33f) > 0.0f) ? 1u : 0u;
        zw |= z << t2;
        if (z) v = 0.0f;
        cur = 0.8f * cur + acc[t2][k];
      }
      mOut[(size_t)b * O + obase + k] = zw;  // em-format for next layer
    }
  }
}

extern "C" void kernel_launch(void* const* d_in, const int* in_sizes, int n_in,
                              void* d_out, int out_size, void* d_ws, size_t ws_size,
                              hipStream_t stream)
{
  const float* x  = (const float*)d_in[0];
  const float* w1 = (const float*)d_in[1];
  const float* w2 = (const float*)d_in[2];
  const float* w3 = (const float*)d_in[3];
  const float* w4 = (const float*)d_in[4];
  const float* fs = (const float*)d_in[5];
  const float* es = (const float*)d_in[6];
  float* out = (float*)d_out;
  (void)in_sizes; (void)n_in; (void)out_size;

  // ws: WT (5.9 MB) + em + s1m + s2m + s3m (all em-format words)
  int Bc = 2048;
  auto need = [](int bc) -> size_t {
    return ((size_t)WTOT + (size_t)bc * (2048 + 512 + 512 + 256)) * 4;
  };
  while (Bc > 64 && need(Bc) > ws_size) Bc >>= 1;

  float* WT = (float*)d_ws;
  unsigned* em  = (unsigned*)(WT + WTOT);
  unsigned* s1m = em  + (size_t)Bc * 2048;
  unsigned* s2m = s1m + (size_t)Bc * 512;
  unsigned* s3m = s2m + (size_t)Bc * 512;

  prep_kernel<<<(WTOT + THREADS - 1) / THREADS, THREADS, 0, stream>>>(
      w1, w2, w3, w4, WT);

  for (int b0 = 0; b0 < 2048; b0 += Bc) {
    enc_kernel<<<(Bc * 2048) / THREADS, THREADS, 0, stream>>>(x, fs, em, b0);
    // L1: J=2048 -> O=512, scale = 5*encoder_scalar
    gemm_sparse<512, false><<<Bc / 2, THREADS, 0, stream>>>(
        em, WT + WOFF1, 2048, es, s1m, nullptr, 0);
    // L2: J=512 -> O=512
    gemm_sparse<512, false><<<Bc / 2, THREADS, 0, stream>>>(
        s1m, WT + WOFF2, 512, nullptr, s2m, nullptr, 0);
    // L3: J=512 -> O=256
    gemm_sparse<256, false><<<Bc / 4, THREADS, 0, stream>>>(
        s2m, WT + WOFF3, 512, nullptr, s3m, nullptr, 0);
    // L4 (readout): J=256 -> O=128 (padded), LI epilogue -> out
    gemm_sparse<128, true><<<Bc / 4, THREADS, 0, stream>>>(
        s3m, WT + WOFF4, 256, nullptr, nullptr, out, b0);
  }
}

// Round 12
// 1163.715 us; speedup vs baseline: 1.0349x; 1.0349x over previous
//
#include <hip/hip_runtime.h>
#include <cstddef>

// ---------------------------------------------------------------------------
// SNN forward, feed-forward pipeline. CORRECTNESS CONTRACT: reproduce R3's
// sequential-in-ascending-j fp32 fmaf chain per (t,b,o) (passed, 1.5e-5).
// R10 FACT: fmaf(+0, w, acc) == acc EXACTLY (acc never -0), so skipping
// zero-spike j's is bit-identical.
//
// R10/R11 post-mortem: both landed VALUBusy 50% — NOT barriers/LDS (R11 has
// none). Cause: conditional W load and FMA body share the same condition ->
// compiler merges them -> per active j: load, vmcnt, 128 FMAs = ~200cyc
// exposed latency vs 256cyc FMA = ~55% ceiling. R12: cross-group software
// pipeline — masks prefetched 2 groups ahead, W rows 1 group ahead (conditions
// differ between phases -> no merge; load-to-use distance ~435cyc > L2 200).
//   - j skipped via wave-uniform scalar branch (mask word == 0)
//   - per-t gate on the scalar pipe (av = SGPR operand to v_fmac)
//   - t in registers (acc[32][NAO]); LIF/LI epilogue all-register, no LDS
// R4/R5/R7 lesson: acc static-indexed; pipeline regs kept ~30 (under cap).
// ---------------------------------------------------------------------------

#define THREADS 256

// WT offsets (floats): WT1[2048][512], WT2[512][512], WT3[512][256],
// WT4[256][128] (w4 zero-padded 100->128 cols)
#define WOFF1 0
#define WOFF2 1048576
#define WOFF3 1310720
#define WOFF4 1441792
#define WTOT  1474560

__global__ __launch_bounds__(THREADS) void prep_kernel(
    const float* __restrict__ w1, const float* __restrict__ w2,
    const float* __restrict__ w3, const float* __restrict__ w4,
    float* __restrict__ wt)
{
  int idx = blockIdx.x * THREADS + threadIdx.x;
  if (idx >= WTOT) return;
  if (idx < WOFF2) {
    int j = idx >> 9, o = idx & 511;
    wt[idx] = w1[o * 2048 + j];
  } else if (idx < WOFF3) {
    int r = idx - WOFF2, j = r >> 9, o = r & 511;
    wt[idx] = w2[o * 512 + j];
  } else if (idx < WOFF4) {
    int r = idx - WOFF3, j = r >> 8, o = r & 255;
    wt[idx] = w3[o * 512 + j];
  } else {
    int r = idx - WOFF4, j = r >> 7, o = r & 127;
    wt[idx] = (o < 100) ? w4[o * 256 + j] : 0.0f;
  }
}

// Encoder (verbatim R3 arithmetic); writes em[b][j] word = bits over t.
__global__ __launch_bounds__(THREADS) void enc_kernel(
    const float* __restrict__ x, const float* __restrict__ fscale,
    unsigned* __restrict__ em, int b0)
{
  int idx = blockIdx.x * THREADS + threadIdx.x;
  int b = idx >> 11, j = idx & 2047;
  float c = 2.0f * fscale[0] * x[((size_t)(b0 + b) << 11) + j];
  float v = 0.0f;
  unsigned m = 0u;
#pragma unroll
  for (int t = 0; t < 32; ++t) {
    v = v + 0.1f * (c - v);
    unsigned z = ((v - 0.33f) > 0.0f) ? 1u : 0u;
    m |= z << t;
    if (z) v = 0.0f;
  }
  em[idx] = m;
}

// ---------------------------------------------------------------------------
// Sparse-j fused GEMM(+LIF / +LI readout), LDS-free, group-pipelined.
//   mIn: em-format masks [b][J], word = bits over t (wave-uniform per j)
//   WT:  [j][o] pre-transposed weights (rows L2-resident)
// Block: 4 waves; wave = (b, o-slice); lane owns NAO consecutive o's,
// acc[32][NAO] holds all t. Groups of 4 j; pipeline: masks depth-2, W depth-1.
// ---------------------------------------------------------------------------
template <int O, bool FINAL>
__global__ __launch_bounds__(THREADS, 2) void gemm_sparse(
    const unsigned* __restrict__ mIn, const float* __restrict__ WT,
    int J, const float* __restrict__ es,
    unsigned* __restrict__ mOut, float* __restrict__ out, int bbase)
{
  constexpr int NAO = (O >= 256) ? 4 : 2;    // o's per lane
  constexpr int WPB = O / (64 * NAO);        // waves per b
  constexpr int BPB = 4 / WPB;               // b's per block
  typedef float fv __attribute__((ext_vector_type(NAO)));
  const int tid = threadIdx.x;
  const int lane = tid & 63, wvid = tid >> 6;
  const int b = blockIdx.x * BPB + wvid / WPB;
  const int obase = (wvid % WPB) * (64 * NAO) + lane * NAO;
  const float* const wbase = WT + obase;     // row j at wbase + j*O
  float scalef = es ? 5.0f * es[0] : 1.0f;   // same expr as R3
  const int scale_i =
      __builtin_amdgcn_readfirstlane(__float_as_int(scalef));

  float acc[32][NAO];
#pragma unroll
  for (int t = 0; t < 32; ++t)
#pragma unroll
    for (int k = 0; k < NAO; ++k) acc[t][k] = 0.0f;

  const unsigned* mrow = mIn + (size_t)b * J;
  const int G = J >> 2;                      // groups of 4 j (all even sizes)

  auto mload = [&](int g) -> uint4 {
    return *(const uint4*)(mrow + g * 4);    // wave-uniform address
  };
  auto rfl = [&](uint4 mq, unsigned* w) {
    w[0] = (unsigned)__builtin_amdgcn_readfirstlane((int)mq.x);
    w[1] = (unsigned)__builtin_amdgcn_readfirstlane((int)mq.y);
    w[2] = (unsigned)__builtin_amdgcn_readfirstlane((int)mq.z);
    w[3] = (unsigned)__builtin_amdgcn_readfirstlane((int)mq.w);
  };
  auto wload = [&](int g, const unsigned* w, fv* wv) {
#pragma unroll
    for (int jj = 0; jj < 4; ++jj)
      if (w[jj]) wv[jj] = *(const fv*)(wbase + (size_t)(g * 4 + jj) * O);
  };
  auto fma_group = [&](const unsigned* w, const fv* wv) {
#pragma unroll
    for (int jj = 0; jj < 4; ++jj) {
      if (w[jj]) {                           // wave-uniform scalar branch
#pragma unroll
        for (int t = 0; t < 32; ++t) {
          // av = bit(w,t) ? scale : 0 — scalar-pipe ops, SGPR fmaf operand
          float av = __int_as_float(
              (int)((((int)(w[jj] << (31 - t))) >> 31) & scale_i));
#pragma unroll
          for (int k = 0; k < NAO; ++k)
            acc[t][k] = fmaf(av, wv[jj][k], acc[t][k]);
        }
      }
    }
  };

  // pipeline state: group g (w0,wv0 in use), g+1 (w1 resolved, wv1 loading),
  // g+2 (mask quad mq2 in flight)
  unsigned w0[4], w1[4];
  fv wv0[4], wv1[4];
  {
    uint4 mq0 = mload(0);
    uint4 mq1 = mload(G > 1 ? 1 : 0);
    rfl(mq0, w0);
    wload(0, w0, wv0);
    rfl(mq1, w1);
  }
  for (int g = 0; g < G; ++g) {
    const int gp2 = (g + 2 < G) ? g + 2 : G - 1;
    const int gp1 = (g + 1 < G) ? g + 1 : G - 1;
    uint4 mq2 = mload(gp2);                  // depth-2 mask prefetch
    wload(gp1, w1, wv1);                     // depth-1 W prefetch (cond: w1)
    fma_group(w0, wv0);                      // bodies (cond: w0 — no merge)
#pragma unroll
    for (int jj = 0; jj < 4; ++jj) {         // rotate (static indices)
      w0[jj] = w1[jj];
      wv0[jj] = wv1[jj];
    }
    rfl(mq2, w1);
  }

  // ---- epilogue: all in registers (t lives in the lane), no barriers ----
#pragma unroll
  for (int k = 0; k < NAO; ++k) {
    if (FINAL) {
      float v = 0.0f, cur = 0.0f;
#pragma unroll
      for (int t2 = 0; t2 < 32; ++t2) {      // verbatim R3 out_li
        v = v + 0.1f * (cur - v);
        cur = 0.8f * cur + acc[t2][k];
      }
      int o = obase + k;
      if (o < 100) out[(size_t)(bbase + b) * 100 + o] = v;
    } else {
      float v = 0.0f, cur = 0.0f;
      unsigned zw = 0u;
#pragma unroll
      for (int t2 = 0; t2 < 32; ++t2) {      // verbatim R3 lif_int
        v = v + 0.1f * (cur - v);
        unsigned z = ((v - 0.33f) > 0.0f) ? 1u : 0u;
        zw |= z << t2;
        if (z) v = 0.0f;
        cur = 0.8f * cur + acc[t2][k];
      }
      mOut[(size_t)b * O + obase + k] = zw;  // em-format for next layer
    }
  }
}

extern "C" void kernel_launch(void* const* d_in, const int* in_sizes, int n_in,
                              void* d_out, int out_size, void* d_ws, size_t ws_size,
                              hipStream_t stream)
{
  const float* x  = (const float*)d_in[0];
  const float* w1 = (const float*)d_in[1];
  const float* w2 = (const float*)d_in[2];
  const float* w3 = (const float*)d_in[3];
  const float* w4 = (const float*)d_in[4];
  const float* fs = (const float*)d_in[5];
  const float* es = (const float*)d_in[6];
  float* out = (float*)d_out;
  (void)in_sizes; (void)n_in; (void)out_size;

  // ws: WT (5.9 MB) + em + s1m + s2m + s3m (all em-format words)
  int Bc = 2048;
  auto need = [](int bc) -> size_t {
    return ((size_t)WTOT + (size_t)bc * (2048 + 512 + 512 + 256)) * 4;
  };
  while (Bc > 64 && need(Bc) > ws_size) Bc >>= 1;

  float* WT = (float*)d_ws;
  unsigned* em  = (unsigned*)(WT + WTOT);
  unsigned* s1m = em  + (size_t)Bc * 2048;
  unsigned* s2m = s1m + (size_t)Bc * 512;
  unsigned* s3m = s2m + (size_t)Bc * 512;

  prep_kernel<<<(WTOT + THREADS - 1) / THREADS, THREADS, 0, stream>>>(
      w1, w2, w3, w4, WT);

  for (int b0 = 0; b0 < 2048; b0 += Bc) {
    enc_kernel<<<(Bc * 2048) / THREADS, THREADS, 0, stream>>>(x, fs, em, b0);
    // L1: J=2048 -> O=512, scale = 5*encoder_scalar
    gemm_sparse<512, false><<<Bc / 2, THREADS, 0, stream>>>(
        em, WT + WOFF1, 2048, es, s1m, nullptr, 0);
    // L2: J=512 -> O=512
    gemm_sparse<512, false><<<Bc / 2, THREADS, 0, stream>>>(
        s1m, WT + WOFF2, 512, nullptr, s2m, nullptr, 0);
    // L3: J=512 -> O=256
    gemm_sparse<256, false><<<Bc / 4, THREADS, 0, stream>>>(
        s2m, WT + WOFF3, 512, nullptr, s3m, nullptr, 0);
    // L4 (readout): J=256 -> O=128 (padded), LI epilogue -> out
    gemm_sparse<128, true><<<Bc / 4, THREADS, 0, stream>>>(
        s3m, WT + WOFF4, 256, nullptr, nullptr, out, b0);
  }
}

// Round 13
// 1132.997 us; speedup vs baseline: 1.0629x; 1.0271x over previous
//
#include <hip/hip_runtime.h>
#include <cstddef>

// ---------------------------------------------------------------------------
// SNN forward, feed-forward pipeline. CORRECTNESS CONTRACT: reproduce R3's
// sequential-in-ascending-j fp32 fmaf chain per (t,b,o) (passed, 1.5e-5).
// R10 FACT: fmaf(+0, w, acc) == acc EXACTLY (acc never -0), so skipping
// zero-spike j's is bit-identical.
//
// R10/R11: VALUBusy 50% — merged cond-load/cond-body exposed L2 latency.
// R12 (WIN, 1164us): cross-group pipeline -> 59.6%. Residual: 16 rotation
// v_movs + 8 branches per group + load issue chained on mask resolution.
// R13: ping-pong x2 unroll (no rotation movs) + UNCONDITIONAL W-row loads
// (no load branches, no mask->load dependency; inactive-row bytes are L2-hit
// and free) -> only the 4 FMA-body branches per group remain.
//   - j skipped via wave-uniform scalar branch (mask word == 0)
//   - per-t gate on the scalar pipe (av = SGPR operand to v_fmac)
//   - t in registers (acc[32][NAO]); LIF/LI epilogue all-register, no LDS
// R4/R5/R7 lesson: acc static-indexed; staging regs bounded (~180 total).
// ---------------------------------------------------------------------------

#define THREADS 256

// WT offsets (floats): WT1[2048][512], WT2[512][512], WT3[512][256],
// WT4[256][128] (w4 zero-padded 100->128 cols)
#define WOFF1 0
#define WOFF2 1048576
#define WOFF3 1310720
#define WOFF4 1441792
#define WTOT  1474560

__global__ __launch_bounds__(THREADS) void prep_kernel(
    const float* __restrict__ w1, const float* __restrict__ w2,
    const float* __restrict__ w3, const float* __restrict__ w4,
    float* __restrict__ wt)
{
  int idx = blockIdx.x * THREADS + threadIdx.x;
  if (idx >= WTOT) return;
  if (idx < WOFF2) {
    int j = idx >> 9, o = idx & 511;
    wt[idx] = w1[o * 2048 + j];
  } else if (idx < WOFF3) {
    int r = idx - WOFF2, j = r >> 9, o = r & 511;
    wt[idx] = w2[o * 512 + j];
  } else if (idx < WOFF4) {
    int r = idx - WOFF3, j = r >> 8, o = r & 255;
    wt[idx] = w3[o * 512 + j];
  } else {
    int r = idx - WOFF4, j = r >> 7, o = r & 127;
    wt[idx] = (o < 100) ? w4[o * 256 + j] : 0.0f;
  }
}

// Encoder (verbatim R3 arithmetic); writes em[b][j] word = bits over t.
__global__ __launch_bounds__(THREADS) void enc_kernel(
    const float* __restrict__ x, const float* __restrict__ fscale,
    unsigned* __restrict__ em, int b0)
{
  int idx = blockIdx.x * THREADS + threadIdx.x;
  int b = idx >> 11, j = idx & 2047;
  float c = 2.0f * fscale[0] * x[((size_t)(b0 + b) << 11) + j];
  float v = 0.0f;
  unsigned m = 0u;
#pragma unroll
  for (int t = 0; t < 32; ++t) {
    v = v + 0.1f * (c - v);
    unsigned z = ((v - 0.33f) > 0.0f) ? 1u : 0u;
    m |= z << t;
    if (z) v = 0.0f;
  }
  em[idx] = m;
}

// ---------------------------------------------------------------------------
// Sparse-j fused GEMM(+LIF / +LI readout), LDS-free, ping-pong pipelined.
//   mIn: em-format masks [b][J], word = bits over t (wave-uniform per j)
//   WT:  [j][o] pre-transposed weights (rows L2-resident)
// Block: 4 waves; wave = (b, o-slice); lane owns NAO consecutive o's,
// acc[32][NAO] holds all t. Groups of 4 j; W loads unconditional, depth-1;
// masks depth-2; FMA bodies conditional (the sparsity win).
// ---------------------------------------------------------------------------
template <int O, bool FINAL>
__global__ __launch_bounds__(THREADS, 2) void gemm_sparse(
    const unsigned* __restrict__ mIn, const float* __restrict__ WT,
    int J, const float* __restrict__ es,
    unsigned* __restrict__ mOut, float* __restrict__ out, int bbase)
{
  constexpr int NAO = (O >= 256) ? 4 : 2;    // o's per lane
  constexpr int WPB = O / (64 * NAO);        // waves per b
  constexpr int BPB = 4 / WPB;               // b's per block
  typedef float fv __attribute__((ext_vector_type(NAO)));
  const int tid = threadIdx.x;
  const int lane = tid & 63, wvid = tid >> 6;
  const int b = blockIdx.x * BPB + wvid / WPB;
  const int obase = (wvid % WPB) * (64 * NAO) + lane * NAO;
  const float* const wbase = WT + obase;     // row j at wbase + j*O
  float scalef = es ? 5.0f * es[0] : 1.0f;   // same expr as R3
  const int scale_i =
      __builtin_amdgcn_readfirstlane(__float_as_int(scalef));

  float acc[32][NAO];
#pragma unroll
  for (int t = 0; t < 32; ++t)
#pragma unroll
    for (int k = 0; k < NAO; ++k) acc[t][k] = 0.0f;

  const unsigned* mrow = mIn + (size_t)b * J;
  const int G = J >> 2;                      // groups of 4 j (G even: 512/128/128/64)

  auto mload = [&](int g) -> uint4 {
    return *(const uint4*)(mrow + g * 4);    // wave-uniform address
  };
  auto rfl = [&](uint4 mq, unsigned* w) {
    w[0] = (unsigned)__builtin_amdgcn_readfirstlane((int)mq.x);
    w[1] = (unsigned)__builtin_amdgcn_readfirstlane((int)mq.y);
    w[2] = (unsigned)__builtin_amdgcn_readfirstlane((int)mq.z);
    w[3] = (unsigned)__builtin_amdgcn_readfirstlane((int)mq.w);
  };
  auto wloadU = [&](int g, fv* wv) {         // UNCONDITIONAL: no branches,
#pragma unroll                               // no mask dependency
    for (int jj = 0; jj < 4; ++jj)
      wv[jj] = *(const fv*)(wbase + (size_t)(g * 4 + jj) * O);
  };
  auto fma_group = [&](const unsigned* w, const fv* wv) {
#pragma unroll
    for (int jj = 0; jj < 4; ++jj) {
      if (w[jj]) {                           // wave-uniform scalar branch
#pragma unroll
        for (int t = 0; t < 32; ++t) {
          // av = bit(w,t) ? scale : 0 — scalar-pipe ops, SGPR fmaf operand
          float av = __int_as_float(
              (int)((((int)(w[jj] << (31 - t))) >> 31) & scale_i));
#pragma unroll
          for (int k = 0; k < NAO; ++k)
            acc[t][k] = fmaf(av, wv[jj][k], acc[t][k]);
        }
      }
    }
  };

  // ping-pong pipeline: A holds group g, B holds g+1; no rotation copies
  unsigned wA[4], wB[4];
  fv wvA[4], wvB[4];
  {
    uint4 mq0 = mload(0);
    uint4 mq1 = mload(G > 1 ? 1 : 0);
    rfl(mq0, wA);
    rfl(mq1, wB);
    wloadU(0, wvA);
  }
  for (int g = 0; g < G; g += 2) {
    const int g2 = (g + 2 < G) ? g + 2 : G - 1;
    const int g3 = (g + 3 < G) ? g + 3 : G - 1;
    uint4 mq2 = mload(g2);                   // depth-2 mask prefetch
    wloadU(g + 1, wvB);                      // unconditional W prefetch
    fma_group(wA, wvA);                      // bodies for g (cond: wA)
    rfl(mq2, wA);                            // wA := masks(g+2)
    uint4 mq3 = mload(g3);
    wloadU(g2, wvA);                         // unconditional W prefetch
    fma_group(wB, wvB);                      // bodies for g+1 (cond: wB)
    rfl(mq3, wB);                            // wB := masks(g+3)
  }

  // ---- epilogue: all in registers (t lives in the lane), no barriers ----
#pragma unroll
  for (int k = 0; k < NAO; ++k) {
    if (FINAL) {
      float v = 0.0f, cur = 0.0f;
#pragma unroll
      for (int t2 = 0; t2 < 32; ++t2) {      // verbatim R3 out_li
        v = v + 0.1f * (cur - v);
        cur = 0.8f * cur + acc[t2][k];
      }
      int o = obase + k;
      if (o < 100) out[(size_t)(bbase + b) * 100 + o] = v;
    } else {
      float v = 0.0f, cur = 0.0f;
      unsigned zw = 0u;
#pragma unroll
      for (int t2 = 0; t2 < 32; ++t2) {      // verbatim R3 lif_int
        v = v + 0.1f * (cur - v);
        unsigned z = ((v - 0.33f) > 0.0f) ? 1u : 0u;
        zw |= z << t2;
        if (z) v = 0.0f;
        cur = 0.8f * cur + acc[t2][k];
      }
      mOut[(size_t)b * O + obase + k] = zw;  // em-format for next layer
    }
  }
}

extern "C" void kernel_launch(void* const* d_in, const int* in_sizes, int n_in,
                              void* d_out, int out_size, void* d_ws, size_t ws_size,
                              hipStream_t stream)
{
  const float* x  = (const float*)d_in[0];
  const float* w1 = (const float*)d_in[1];
  const float* w2 = (const float*)d_in[2];
  const float* w3 = (const float*)d_in[3];
  const float* w4 = (const float*)d_in[4];
  const float* fs = (const float*)d_in[5];
  const float* es = (const float*)d_in[6];
  float* out = (float*)d_out;
  (void)in_sizes; (void)n_in; (void)out_size;

  // ws: WT (5.9 MB) + em + s1m + s2m + s3m (all em-format words)
  int Bc = 2048;
  auto need = [](int bc) -> size_t {
    return ((size_t)WTOT + (size_t)bc * (2048 + 512 + 512 + 256)) * 4;
  };
  while (Bc > 64 && need(Bc) > ws_size) Bc >>= 1;

  float* WT = (float*)d_ws;
  unsigned* em  = (unsigned*)(WT + WTOT);
  unsigned* s1m = em  + (size_t)Bc * 2048;
  unsigned* s2m = s1m + (size_t)Bc * 512;
  unsigned* s3m = s2m + (size_t)Bc * 512;

  prep_kernel<<<(WTOT + THREADS - 1) / THREADS, THREADS, 0, stream>>>(
      w1, w2, w3, w4, WT);

  for (int b0 = 0; b0 < 2048; b0 += Bc) {
    enc_kernel<<<(Bc * 2048) / THREADS, THREADS, 0, stream>>>(x, fs, em, b0);
    // L1: J=2048 -> O=512, scale = 5*encoder_scalar
    gemm_sparse<512, false><<<Bc / 2, THREADS, 0, stream>>>(
        em, WT + WOFF1, 2048, es, s1m, nullptr, 0);
    // L2: J=512 -> O=512
    gemm_sparse<512, false><<<Bc / 2, THREADS, 0, stream>>>(
        s1m, WT + WOFF2, 512, nullptr, s2m, nullptr, 0);
    // L3: J=512 -> O=256
    gemm_sparse<256, false><<<Bc / 4, THREADS, 0, stream>>>(
        s2m, WT + WOFF3, 512, nullptr, s3m, nullptr, 0);
    // L4 (readout): J=256 -> O=128 (padded), LI epilogue -> out
    gemm_sparse<128, true><<<Bc / 4, THREADS, 0, stream>>>(
        s3m, WT + WOFF4, 256, nullptr, nullptr, out, b0);
  }
}